// Round 5
// baseline (6608.628 us; speedup 1.0000x reference)
//
#include <hip/hip_runtime.h>
#include <math.h>

#define CC 20
#define BB 256
#define HH 10
#define SS 64
#define AA 16
#define HD 128
#define RH 64
#define CBR (CC*BB)      // 5120 rows
#define NSNN 15

// Replicate npy_logaddexpf(u, 0.f): float32 chain, expf/log1pf at
// correctly-rounded level via f64 internals. (Verified bit-exact in round 4.)
__device__ __forceinline__ float softplus_np(float u) {
    if (u > 0.0f) {
        float ef = (float)exp((double)(-u));
        float l1 = (float)log1p((double)ef);
        return __fadd_rn(u, l1);
    } else if (u < 0.0f) {
        float ef = (float)exp((double)u);
        return (float)log1p((double)ef);
    } else {
        return 0.69314718055994530942f;
    }
}

// One block = one rollout row (cb = c*B + b), full 10-step rollout + reward
// fused. 128 threads, thread j = hidden unit j. All dots are single
// sequential-k fmaf chains; all elementwise ops separately rounded — keeps
// bit-exact equality with the np-f32 reference (round-4 verified).
//
// SNN inner product optimization (bit-exact): mem1 depends only on cur, so
// compute the 15-bit spike mask per unit first, then accumulate all 15
// cur2[t] in ONE k-ascending pass. fmaf(sv in {0,1}, w, acc) with sv=0 is an
// exact identity (acc is never -0 here), so each cur2[t] equals the
// reference's sequential chain bit-for-bit.
__global__ __launch_bounds__(128) void rollout_kernel(
    const float* __restrict__ current_state,   // [B,S]
    const float* __restrict__ actions,         // [C,B,H,A]
    const float* __restrict__ noise,           // [C,B,H,S]
    const float* __restrict__ Wse, const float* __restrict__ bse,
    const float* __restrict__ Wae, const float* __restrict__ bae,
    const float* __restrict__ W1,  const float* __restrict__ b1,
    const float* __restrict__ W2,  const float* __restrict__ b2,
    const float* __restrict__ Wdec, const float* __restrict__ bdec,
    const float* __restrict__ Wunc, const float* __restrict__ bunc,
    const float* __restrict__ Wr1, const float* __restrict__ br1,
    const float* __restrict__ Wr2, const float* __restrict__ br2,
    const float* __restrict__ Wr3, const float* __restrict__ br3,
    float* __restrict__ cum)                   // [CB]
{
    const int cb = blockIdx.x;
    const int j  = threadIdx.x;

    __shared__ float    s_state[SS];
    __shared__ float    s_sae[2*HD];
    __shared__ unsigned s_mask[HD];
    __shared__ float    s_mem2[HD];
    __shared__ float    s_mu[2*SS];      // [0..63]=mean, [64..127]=u
    __shared__ float    s_x[SS + AA];
    __shared__ float    s_h[RH];
    __shared__ float    s_h2[RH];

    if (j < SS) s_state[j] = current_state[(size_t)(cb % BB)*SS + j];

    float total = 0.0f;                  // used by thread 0 only

    for (int h = 0; h < HH; h++) {
        __syncthreads();                 // s_state (and prior-iter LDS) ready

        // ---- se = relu(state @ Wse + bse): sequential-k single chain
        float acc = 0.0f;
        for (int i = 0; i < SS; i++)
            acc = fmaf(s_state[i], Wse[i*HD + j], acc);
        float se = fmaxf(__fadd_rn(acc, bse[j]), 0.0f);

        // ---- ae = relu(act @ Wae + bae)
        const float* act = actions + ((size_t)cb*HH + h)*AA;
        acc = 0.0f;
        for (int i = 0; i < AA; i++)
            acc = fmaf(act[i], Wae[i*HD + j], acc);
        float ae = fmaxf(__fadd_rn(acc, bae[j]), 0.0f);

        s_sae[j]      = se;
        s_sae[HD + j] = ae;
        __syncthreads();

        // ---- cur = concat(se, ae) @ W1 + b1 (constant across SNN steps)
        acc = 0.0f;
        for (int i = 0; i < 2*HD; i++)
            acc = fmaf(s_sae[i], W1[i*HD + j], acc);
        const float cur = __fadd_rn(acc, b1[j]);

        // ---- mem1 recurrence -> 15-bit spike mask (exact round-4 op order)
        unsigned mask = 0u;
        float m1 = 0.0f;
        #pragma unroll
        for (int t = 0; t < NSNN; t++) {
            float sp1old = (__fsub_rn(m1, 1.0f) > 0.0f) ? 1.0f : 0.0f;
            m1 = __fsub_rn(__fadd_rn(__fmul_rn(0.9f, m1), cur), sp1old);
            if (__fsub_rn(m1, 1.0f) > 0.0f) mask |= (1u << t);
        }
        s_mask[j] = mask;
        __syncthreads();

        // ---- cur2[t] = spk[t] @ W2, all t in one k-ascending pass
        float cur2[NSNN];
        #pragma unroll
        for (int t = 0; t < NSNN; t++) cur2[t] = 0.0f;

        for (int k = 0; k < HD; k++) {
            unsigned m = (unsigned)__builtin_amdgcn_readfirstlane((int)s_mask[k]);
            if (m == 0u) continue;                 // wave-uniform; exact-0 terms
            float w = W2[k*HD + j];
            #pragma unroll
            for (int t = 0; t < NSNN; t++) {
                float sv = ((m >> t) & 1u) ? 1.0f : 0.0f;
                cur2[t] = fmaf(sv, w, cur2[t]);    // identity when sv==0
            }
        }

        // ---- mem2 recurrence (exact round-4 op order)
        const float b2j = b2[j];
        float m2 = 0.0f;
        #pragma unroll
        for (int t = 0; t < NSNN; t++) {
            float c2 = __fadd_rn(cur2[t], b2j);
            float sp2old = (__fsub_rn(m2, 1.0f) > 0.0f) ? 1.0f : 0.0f;
            m2 = __fsub_rn(__fadd_rn(__fmul_rn(0.9f, m2), c2), sp2old);
        }
        s_mem2[j] = m2;
        __syncthreads();

        // ---- decode, wave-split: threads 0..63 mean, 64..127 unc
        {
            const float* W    = (j < SS) ? Wdec : Wunc;
            const float* bias = (j < SS) ? bdec : bunc;
            int o = j & (SS - 1);
            float c = 0.0f;
            for (int n = 0; n < HD; n++)
                c = fmaf(s_mem2[n], W[n*SS + o], c);
            s_mu[j] = __fadd_rn(c, bias[o]);
        }
        __syncthreads();

        // ---- sample next state; feed both next world step and reward
        if (j < SS) {
            float mean = s_mu[j];
            float u    = s_mu[SS + j];
            float var  = softplus_np(u);
            float sv   = sqrtf(__fadd_rn(var, 1e-8f));
            float nz   = noise[((size_t)cb*HH + h)*SS + j];
            float ns   = __fadd_rn(mean, __fmul_rn(nz, sv));
            s_x[j]     = ns;
            s_state[j] = ns;
        }
        if (j < AA) s_x[SS + j] = act[j];
        __syncthreads();

        // ---- reward: relu(x@Wr1+br1) -> relu(@Wr2+br2) -> @Wr3+br3
        if (j < RH) {
            float a = 0.0f;
            for (int i = 0; i < SS + AA; i++)
                a = fmaf(s_x[i], Wr1[i*RH + j], a);
            s_h[j] = fmaxf(__fadd_rn(a, br1[j]), 0.0f);
        }
        __syncthreads();
        if (j < RH) {
            float g = 0.0f;
            for (int i = 0; i < RH; i++)
                g = fmaf(s_h[i], Wr2[i*RH + j], g);
            s_h2[j] = fmaxf(__fadd_rn(g, br2[j]), 0.0f);
        }
        __syncthreads();
        if (j == 0) {
            float r = 0.0f;
            for (int k = 0; k < RH; k++)
                r = fmaf(s_h2[k], Wr3[k], r);
            r = __fadd_rn(r, br3[0]);
            total = __fadd_rn(total, r);           // sequential sum over h
        }
        // next-iteration LDS writes are fenced by the loop-top __syncthreads
    }
    if (j == 0) cum[cb] = total;
}

// One block per batch element b: f32 argmax over C (strict > = first max),
// gather best action. (Unchanged from round 4 — bit-exact.)
__global__ __launch_bounds__(64) void select_kernel(
    const float* __restrict__ cum,      // [CB], cb = c*B + b
    const float* __restrict__ actions,  // [C,B,H,A]
    float* __restrict__ out)            // [B*H*A] actions then [B] values
{
    const int b = blockIdx.x;
    const int j = threadIdx.x;
    __shared__ int s_c;

    if (j == 0) {
        float best = cum[b];            // c = 0
        int bc = 0;
        for (int c = 1; c < CC; c++) {
            float v = cum[(size_t)c*BB + b];
            if (v > best) { best = v; bc = c; }
        }
        s_c = bc;
        out[(size_t)BB*HH*AA + b] = best;
    }
    __syncthreads();
    const int bc = s_c;
    const float* src = actions + ((size_t)bc*BB + b)*HH*AA;
    for (int i = j; i < HH*AA; i += 64) out[(size_t)b*HH*AA + i] = src[i];
}

extern "C" void kernel_launch(void* const* d_in, const int* in_sizes, int n_in,
                              void* d_out, int out_size, void* d_ws, size_t ws_size,
                              hipStream_t stream)
{
    const float* current_state = (const float*)d_in[0];
    const float* actions = (const float*)d_in[1];
    const float* noise   = (const float*)d_in[2];
    const float* Wse = (const float*)d_in[3];
    const float* bse = (const float*)d_in[4];
    const float* Wae = (const float*)d_in[5];
    const float* bae = (const float*)d_in[6];
    const float* W1  = (const float*)d_in[7];
    const float* b1  = (const float*)d_in[8];
    const float* W2  = (const float*)d_in[9];
    const float* b2  = (const float*)d_in[10];
    const float* Wdec = (const float*)d_in[11];
    const float* bdec = (const float*)d_in[12];
    const float* Wunc = (const float*)d_in[13];
    const float* bunc = (const float*)d_in[14];
    const float* Wr1 = (const float*)d_in[15];
    const float* br1 = (const float*)d_in[16];
    const float* Wr2 = (const float*)d_in[17];
    const float* br2 = (const float*)d_in[18];
    const float* Wr3 = (const float*)d_in[19];
    const float* br3 = (const float*)d_in[20];

    float* cum = (float*)d_ws;                          // 5120 f32

    rollout_kernel<<<CBR, HD, 0, stream>>>(current_state, actions, noise,
        Wse, bse, Wae, bae, W1, b1, W2, b2, Wdec, bdec, Wunc, bunc,
        Wr1, br1, Wr2, br2, Wr3, br3, cum);
    select_kernel<<<BB, 64, 0, stream>>>(cum, actions, (float*)d_out);
}

// Round 6
// 4763.375 us; speedup vs baseline: 1.3874x; 1.3874x over previous
//
#include <hip/hip_runtime.h>
#include <math.h>

#define CC 20
#define BB 256
#define HH 10
#define SS 64
#define AA 16
#define HD 128
#define RH 64
#define CBR (CC*BB)      // 5120 rows
#define NSNN 15

// Replicate npy_logaddexpf(u, 0.f): float32 chain, expf/log1pf at
// correctly-rounded level via f64 internals. (Verified bit-exact rounds 4-5.)
__device__ __forceinline__ float softplus_np(float u) {
    if (u > 0.0f) {
        float ef = (float)exp((double)(-u));
        float l1 = (float)log1p((double)ef);
        return __fadd_rn(u, l1);
    } else if (u < 0.0f) {
        float ef = (float)exp((double)u);
        return (float)log1p((double)ef);
    } else {
        return 0.69314718055994530942f;
    }
}

// One block = one rollout row (cb = c*B + b), full 10-step rollout + reward
// fused. 128 threads, thread j = hidden unit j. All dots are single
// sequential-k fmaf chains; all elementwise ops separately rounded — bit-exact
// vs the np-f32 reference (verified rounds 4 and 5).
//
// Scheduling changes vs round 5 (numerics untouched):
//  - launch_bounds(128,4): cap VGPRs at 128 (round 5 hit 196 -> 12% occupancy)
//  - spike masks cached in registers; per-k wave-uniform mask via readlane
//    (SALU, no LDS latency on the control path)
//  - W2 loads prefetched in chunks of 8 to amortize L2 latency
__global__ __launch_bounds__(128, 4) void rollout_kernel(
    const float* __restrict__ current_state,   // [B,S]
    const float* __restrict__ actions,         // [C,B,H,A]
    const float* __restrict__ noise,           // [C,B,H,S]
    const float* __restrict__ Wse, const float* __restrict__ bse,
    const float* __restrict__ Wae, const float* __restrict__ bae,
    const float* __restrict__ W1,  const float* __restrict__ b1,
    const float* __restrict__ W2,  const float* __restrict__ b2,
    const float* __restrict__ Wdec, const float* __restrict__ bdec,
    const float* __restrict__ Wunc, const float* __restrict__ bunc,
    const float* __restrict__ Wr1, const float* __restrict__ br1,
    const float* __restrict__ Wr2, const float* __restrict__ br2,
    const float* __restrict__ Wr3, const float* __restrict__ br3,
    float* __restrict__ cum)                   // [CB]
{
    const int cb = blockIdx.x;
    const int j  = threadIdx.x;

    __shared__ float    s_state[SS];
    __shared__ float    s_sae[2*HD];
    __shared__ unsigned s_mask[HD];
    __shared__ float    s_mem2[HD];
    __shared__ float    s_mu[2*SS];      // [0..63]=mean, [64..127]=u
    __shared__ float    s_x[SS + AA];
    __shared__ float    s_h[RH];
    __shared__ float    s_h2[RH];

    if (j < SS) s_state[j] = current_state[(size_t)(cb % BB)*SS + j];

    float total = 0.0f;                  // thread 0 only

    for (int h = 0; h < HH; h++) {
        __syncthreads();                 // s_state (and prior-iter LDS) ready

        // ---- se = relu(state @ Wse + bse): sequential-k single chain
        float acc = 0.0f;
        for (int i = 0; i < SS; i++)
            acc = fmaf(s_state[i], Wse[i*HD + j], acc);
        float se = fmaxf(__fadd_rn(acc, bse[j]), 0.0f);

        // ---- ae = relu(act @ Wae + bae)
        const float* act = actions + ((size_t)cb*HH + h)*AA;
        acc = 0.0f;
        for (int i = 0; i < AA; i++)
            acc = fmaf(act[i], Wae[i*HD + j], acc);
        float ae = fmaxf(__fadd_rn(acc, bae[j]), 0.0f);

        s_sae[j]      = se;
        s_sae[HD + j] = ae;
        __syncthreads();

        // ---- cur = concat(se, ae) @ W1 + b1 (constant across SNN steps)
        acc = 0.0f;
        for (int i = 0; i < 2*HD; i++)
            acc = fmaf(s_sae[i], W1[i*HD + j], acc);
        const float cur = __fadd_rn(acc, b1[j]);

        // ---- mem1 recurrence -> 15-bit spike mask (exact op order)
        unsigned mask = 0u;
        float m1 = 0.0f;
        #pragma unroll
        for (int t = 0; t < NSNN; t++) {
            float sp1old = (__fsub_rn(m1, 1.0f) > 0.0f) ? 1.0f : 0.0f;
            m1 = __fsub_rn(__fadd_rn(__fmul_rn(0.9f, m1), cur), sp1old);
            if (__fsub_rn(m1, 1.0f) > 0.0f) mask |= (1u << t);
        }
        s_mask[j] = mask;
        __syncthreads();

        // ---- cache all 128 masks in 2 VGPRs per lane (one LDS round-trip)
        const int lane = j & 63;
        unsigned mlo = s_mask[lane];
        unsigned mhi = s_mask[64 + lane];

        // ---- cur2[t] = spk[t] @ W2, one k-ascending pass, all t at once.
        // fmaf(sv in {0,1}, w, acc) with sv=0 is an exact identity, so each
        // cur2[t] equals the reference's sequential chain bit-for-bit.
        float cur2[NSNN];
        #pragma unroll
        for (int t = 0; t < NSNN; t++) cur2[t] = 0.0f;

        const float* W2j = W2 + j;
        #pragma unroll
        for (int half = 0; half < 2; half++) {
            unsigned mv = half ? mhi : mlo;
            for (int kc = 0; kc < 64; kc += 8) {           // rolled chunk loop
                float wv[8];
                #pragma unroll
                for (int i = 0; i < 8; i++)
                    wv[i] = W2j[(half*64 + kc + i)*HD];    // 8-deep prefetch
                #pragma unroll
                for (int i = 0; i < 8; i++) {
                    unsigned m = (unsigned)__builtin_amdgcn_readlane((int)mv, kc + i);
                    if (m == 0u) continue;                 // uniform, SALU-fast
                    #pragma unroll
                    for (int t = 0; t < NSNN; t++) {
                        float sv = __uint_as_float(((m >> t) & 1u) * 0x3f800000u);
                        cur2[t] = fmaf(sv, wv[i], cur2[t]);
                    }
                }
            }
        }

        // ---- mem2 recurrence (exact op order)
        const float b2j = b2[j];
        float m2 = 0.0f;
        #pragma unroll
        for (int t = 0; t < NSNN; t++) {
            float c2 = __fadd_rn(cur2[t], b2j);
            float sp2old = (__fsub_rn(m2, 1.0f) > 0.0f) ? 1.0f : 0.0f;
            m2 = __fsub_rn(__fadd_rn(__fmul_rn(0.9f, m2), c2), sp2old);
        }
        s_mem2[j] = m2;
        __syncthreads();

        // ---- decode, wave-split: threads 0..63 mean, 64..127 unc
        {
            const float* W    = (j < SS) ? Wdec : Wunc;
            const float* bias = (j < SS) ? bdec : bunc;
            int o = j & (SS - 1);
            float c = 0.0f;
            for (int n = 0; n < HD; n++)
                c = fmaf(s_mem2[n], W[n*SS + o], c);
            s_mu[j] = __fadd_rn(c, bias[o]);
        }
        __syncthreads();

        // ---- sample next state; feed both next world step and reward
        if (j < SS) {
            float mean = s_mu[j];
            float u    = s_mu[SS + j];
            float var  = softplus_np(u);
            float sv   = sqrtf(__fadd_rn(var, 1e-8f));
            float nz   = noise[((size_t)cb*HH + h)*SS + j];
            float ns   = __fadd_rn(mean, __fmul_rn(nz, sv));
            s_x[j]     = ns;
            s_state[j] = ns;
        }
        if (j < AA) s_x[SS + j] = act[j];
        __syncthreads();

        // ---- reward: relu(x@Wr1+br1) -> relu(@Wr2+br2) -> @Wr3+br3
        if (j < RH) {
            float a = 0.0f;
            for (int i = 0; i < SS + AA; i++)
                a = fmaf(s_x[i], Wr1[i*RH + j], a);
            s_h[j] = fmaxf(__fadd_rn(a, br1[j]), 0.0f);
        }
        __syncthreads();
        if (j < RH) {
            float g = 0.0f;
            for (int i = 0; i < RH; i++)
                g = fmaf(s_h[i], Wr2[i*RH + j], g);
            s_h2[j] = fmaxf(__fadd_rn(g, br2[j]), 0.0f);
        }
        __syncthreads();
        if (j == 0) {
            float r = 0.0f;
            for (int k = 0; k < RH; k++)
                r = fmaf(s_h2[k], Wr3[k], r);
            r = __fadd_rn(r, br3[0]);
            total = __fadd_rn(total, r);           // sequential sum over h
        }
    }
    if (j == 0) cum[cb] = total;
}

// One block per batch element b: f32 argmax over C (strict > = first max),
// gather best action. (Bit-exact, unchanged.)
__global__ __launch_bounds__(64) void select_kernel(
    const float* __restrict__ cum,      // [CB], cb = c*B + b
    const float* __restrict__ actions,  // [C,B,H,A]
    float* __restrict__ out)            // [B*H*A] actions then [B] values
{
    const int b = blockIdx.x;
    const int j = threadIdx.x;
    __shared__ int s_c;

    if (j == 0) {
        float best = cum[b];            // c = 0
        int bc = 0;
        for (int c = 1; c < CC; c++) {
            float v = cum[(size_t)c*BB + b];
            if (v > best) { best = v; bc = c; }
        }
        s_c = bc;
        out[(size_t)BB*HH*AA + b] = best;
    }
    __syncthreads();
    const int bc = s_c;
    const float* src = actions + ((size_t)bc*BB + b)*HH*AA;
    for (int i = j; i < HH*AA; i += 64) out[(size_t)b*HH*AA + i] = src[i];
}

extern "C" void kernel_launch(void* const* d_in, const int* in_sizes, int n_in,
                              void* d_out, int out_size, void* d_ws, size_t ws_size,
                              hipStream_t stream)
{
    const float* current_state = (const float*)d_in[0];
    const float* actions = (const float*)d_in[1];
    const float* noise   = (const float*)d_in[2];
    const float* Wse = (const float*)d_in[3];
    const float* bse = (const float*)d_in[4];
    const float* Wae = (const float*)d_in[5];
    const float* bae = (const float*)d_in[6];
    const float* W1  = (const float*)d_in[7];
    const float* b1  = (const float*)d_in[8];
    const float* W2  = (const float*)d_in[9];
    const float* b2  = (const float*)d_in[10];
    const float* Wdec = (const float*)d_in[11];
    const float* bdec = (const float*)d_in[12];
    const float* Wunc = (const float*)d_in[13];
    const float* bunc = (const float*)d_in[14];
    const float* Wr1 = (const float*)d_in[15];
    const float* br1 = (const float*)d_in[16];
    const float* Wr2 = (const float*)d_in[17];
    const float* br2 = (const float*)d_in[18];
    const float* Wr3 = (const float*)d_in[19];
    const float* br3 = (const float*)d_in[20];

    float* cum = (float*)d_ws;                          // 5120 f32

    rollout_kernel<<<CBR, HD, 0, stream>>>(current_state, actions, noise,
        Wse, bse, Wae, bae, W1, b1, W2, b2, Wdec, bdec, Wunc, bunc,
        Wr1, br1, Wr2, br2, Wr3, br3, cum);
    select_kernel<<<BB, 64, 0, stream>>>(cum, actions, (float*)d_out);
}